// Round 14
// baseline (235.265 us; speedup 1.0000x reference)
//
#include <hip/hip_runtime.h>
#include <hip/hip_bf16.h>
#include <cstdint>

#define CH 2048
#define NCF 8192          // 4 * CH
#define NJ 24             // 4 pre + 4 post + 16 res
#define RPB 4             // batch rows per group
#define NBLK 512          // persistent blocks (2 per CU)
#define EPS_F 1e-5f
#define SINK_ITERS 20

typedef float v4f __attribute__((ext_vector_type(4)));

__device__ __forceinline__ uint32_t bf16rne(float f) {
    uint32_t u = __float_as_uint(f);
    return (u + 0x7fffu + ((u >> 16) & 1u)) >> 16;
}

// pack 2 f32 -> 2 bf16 in one instruction (lo -> [15:0], hi -> [31:16])
__device__ __forceinline__ uint32_t cvtpk(float lo, float hi) {
    uint32_t r;
    asm("v_cvt_pk_bf16_f32 %0, %1, %2" : "=v"(r) : "v"(lo), "v"(hi));
    return r;
}

// dot of 8 bf16 pairs (packed in uint4) via v_dot2_f32_bf16
__device__ __forceinline__ float dot8(const uint4& x, const uint4& p, float acc) {
    asm("v_dot2_f32_bf16 %0, %1, %2, %0" : "+v"(acc) : "v"(x.x), "v"(p.x));
    asm("v_dot2_f32_bf16 %0, %1, %2, %0" : "+v"(acc) : "v"(x.y), "v"(p.y));
    asm("v_dot2_f32_bf16 %0, %1, %2, %0" : "+v"(acc) : "v"(x.z), "v"(p.z));
    asm("v_dot2_f32_bf16 %0, %1, %2, %0" : "+v"(acc) : "v"(x.w), "v"(p.w));
    return acc;
}

// ---------------------------------------------------------------------------
// Prep: phiW[j][k] = bf16( alpha_j * w[k % CH] * phi_j[k] ),  j in [0,24)
// ---------------------------------------------------------------------------
__global__ void __launch_bounds__(256) prep_phi_kernel(
    const float* __restrict__ w,
    const float* __restrict__ phi_pre,
    const float* __restrict__ phi_post,
    const float* __restrict__ phi_res,
    const float* __restrict__ alpha_pre,
    const float* __restrict__ alpha_post,
    const float* __restrict__ alpha_res,
    uint16_t* __restrict__ phiW)
{
    int idx = blockIdx.x * 256 + threadIdx.x;
    if (idx >= NJ * NCF) return;
    int j = idx / NCF;
    int k = idx - j * NCF;
    int c = k & (CH - 1);
    float v, a;
    if (j < 4)      { v = phi_pre[j * NCF + k];        a = alpha_pre[0]; }
    else if (j < 8) { v = phi_post[(j - 4) * NCF + k]; a = alpha_post[0]; }
    else            { v = phi_res[(j - 8) * NCF + k];  a = alpha_res[0]; }
    phiW[idx] = (uint16_t)bf16rne(v * a * w[c]);
}

// ---------------------------------------------------------------------------
// Main fused kernel, PERSISTENT + PIPELINED. 512 threads (8 waves),
// grid-stride over groups of 4 rows. Next group's x is prefetched into
// registers right after the current dot loop, hiding HBM latency under the
// reduction + Sinkhorn + epilogue. LDS: raw bf16 x, 64 KiB -> 2 blocks/CU.
// ---------------------------------------------------------------------------
__global__ void __launch_bounds__(512, 2) mhc_main_kernel(
    const float* __restrict__ x,
    const uint16_t* __restrict__ phiW,
    const float* __restrict__ b_pre,
    const float* __restrict__ b_post,
    const float* __restrict__ b_res,
    float* __restrict__ out,
    int ngroups)
{
    const int t = threadIdx.x;
    const int lane = t & 63;
    const int wave = t >> 6;              // 0..7

    __shared__ uint32_t xn[RPB][NCF / 2]; // raw bf16 x, 4 rows, 64 KiB
    __shared__ float4 red[RPB][8];
    __shared__ float H[RPB][24] __attribute__((aligned(16)));
    __shared__ float MS[RPB][16] __attribute__((aligned(16)));

    // per-wave projection-row biases (j = 3*wave + jl), hoisted
    float bias[3];
    #pragma unroll
    for (int jl = 0; jl < 3; ++jl) {
        int j = 3 * wave + jl;
        bias[jl] = (j < 4) ? b_pre[j] : (j < 8) ? b_post[j - 4] : b_res[j - 8];
    }

    const float4* x4 = reinterpret_cast<const float4*>(x);

    // initial prefetch: group blockIdx.x
    float4 xr[16];                        // [r*4+jj]
    {
        const float4* xp = x4 + (long)blockIdx.x * RPB * 2048;
        #pragma unroll
        for (int r = 0; r < RPB; ++r)
            #pragma unroll
            for (int jj = 0; jj < 4; ++jj)
                xr[r * 4 + jj] = xp[r * 2048 + t + 512 * jj];
    }

    #pragma unroll 1
    for (long g = blockIdx.x; g < ngroups; g += NBLK) {
        const long b0 = g * RPB;

        // ---- Phase A': regs -> LDS (bf16 pack) + sum-of-squares ----
        {
            float ssv[16];
            #pragma unroll
            for (int r = 0; r < RPB; ++r) {
                #pragma unroll
                for (int jj = 0; jj < 4; ++jj) {
                    float4 v = xr[r * 4 + jj];
                    ssv[r * 4 + jj] = v.x*v.x + v.y*v.y + v.z*v.z + v.w*v.w;
                    *reinterpret_cast<uint2*>(&xn[r][2*t + 1024*jj]) =
                        make_uint2(cvtpk(v.x, v.y), cvtpk(v.z, v.w));
                }
            }
            #pragma unroll
            for (int m = 1; m < 64; m <<= 1)
                #pragma unroll
                for (int i = 0; i < 16; ++i)
                    ssv[i] += __shfl_xor(ssv[i], m, 64);
            if (lane == 0) {
                #pragma unroll
                for (int r = 0; r < RPB; ++r)
                    red[r][wave] = make_float4(ssv[r*4], ssv[r*4+1], ssv[r*4+2], ssv[r*4+3]);
            }
        }
        __syncthreads();

        // ---- SCL redundantly per thread (broadcast LDS reads) ----
        float scl[RPB][4];
        #pragma unroll
        for (int r = 0; r < RPB; ++r) {
            float sx = 0.f, sy = 0.f, sz = 0.f, sw = 0.f;
            #pragma unroll
            for (int w8 = 0; w8 < 8; ++w8) {
                float4 v = red[r][w8];
                sx += v.x; sy += v.y; sz += v.z; sw += v.w;
            }
            scl[r][0] = rsqrtf(sx * (1.0f / CH) + EPS_F);
            scl[r][1] = rsqrtf(sy * (1.0f / CH) + EPS_F);
            scl[r][2] = rsqrtf(sz * (1.0f / CH) + EPS_F);
            scl[r][3] = rsqrtf(sw * (1.0f / CH) + EPS_F);
        }

        // ---- Phase B: wave w dots 4 rows against phi rows 3w..3w+2 ----
        float accT[3][RPB] = {};
        float accS[3][RPB] = {};
        {
            const uint16_t* pw = phiW + (size_t)(wave * 3) * NCF;
            const int kl = 8 * lane;
            const uint4* xr0 = reinterpret_cast<const uint4*>(xn[0]);
            const uint4* xr1 = reinterpret_cast<const uint4*>(xn[1]);
            const uint4* xr2 = reinterpret_cast<const uint4*>(xn[2]);
            const uint4* xr3 = reinterpret_cast<const uint4*>(xn[3]);

            uint4 pA0 = *reinterpret_cast<const uint4*>(pw + 0 * NCF + kl);
            uint4 pA1 = *reinterpret_cast<const uint4*>(pw + 1 * NCF + kl);
            uint4 pA2 = *reinterpret_cast<const uint4*>(pw + 2 * NCF + kl);
            uint4 xA0 = xr0[lane], xA1 = xr1[lane], xA2 = xr2[lane], xA3 = xr3[lane];

            #pragma unroll
            for (int u = 0; u < 16; u += 2) {
                const int iB = 64 * (u + 1) + lane;
                const int kB = 512 * (u + 1) + kl;
                uint4 pB0 = *reinterpret_cast<const uint4*>(pw + 0 * NCF + kB);
                uint4 pB1 = *reinterpret_cast<const uint4*>(pw + 1 * NCF + kB);
                uint4 pB2 = *reinterpret_cast<const uint4*>(pw + 2 * NCF + kB);
                uint4 xB0 = xr0[iB], xB1 = xr1[iB], xB2 = xr2[iB], xB3 = xr3[iB];

                accS[0][0] = dot8(xA0, pA0, accS[0][0]);
                accS[0][1] = dot8(xA1, pA0, accS[0][1]);
                accS[0][2] = dot8(xA2, pA0, accS[0][2]);
                accS[0][3] = dot8(xA3, pA0, accS[0][3]);
                accS[1][0] = dot8(xA0, pA1, accS[1][0]);
                accS[1][1] = dot8(xA1, pA1, accS[1][1]);
                accS[1][2] = dot8(xA2, pA1, accS[1][2]);
                accS[1][3] = dot8(xA3, pA1, accS[1][3]);
                accS[2][0] = dot8(xA0, pA2, accS[2][0]);
                accS[2][1] = dot8(xA1, pA2, accS[2][1]);
                accS[2][2] = dot8(xA2, pA2, accS[2][2]);
                accS[2][3] = dot8(xA3, pA2, accS[2][3]);

                if (u + 2 < 16) {
                    const int iA = 64 * (u + 2) + lane;
                    const int kA = 512 * (u + 2) + kl;
                    pA0 = *reinterpret_cast<const uint4*>(pw + 0 * NCF + kA);
                    pA1 = *reinterpret_cast<const uint4*>(pw + 1 * NCF + kA);
                    pA2 = *reinterpret_cast<const uint4*>(pw + 2 * NCF + kA);
                    xA0 = xr0[iA]; xA1 = xr1[iA]; xA2 = xr2[iA]; xA3 = xr3[iA];
                }

                accS[0][0] = dot8(xB0, pB0, accS[0][0]);
                accS[0][1] = dot8(xB1, pB0, accS[0][1]);
                accS[0][2] = dot8(xB2, pB0, accS[0][2]);
                accS[0][3] = dot8(xB3, pB0, accS[0][3]);
                accS[1][0] = dot8(xB0, pB1, accS[1][0]);
                accS[1][1] = dot8(xB1, pB1, accS[1][1]);
                accS[1][2] = dot8(xB2, pB1, accS[1][2]);
                accS[1][3] = dot8(xB3, pB1, accS[1][3]);
                accS[2][0] = dot8(xB0, pB2, accS[2][0]);
                accS[2][1] = dot8(xB1, pB2, accS[2][1]);
                accS[2][2] = dot8(xB2, pB2, accS[2][2]);
                accS[2][3] = dot8(xB3, pB2, accS[2][3]);

                if (((u + 1) & 3) == 3) {               // end of stream segment
                    const int s = (u + 1) >> 2;
                    #pragma unroll
                    for (int jl = 0; jl < 3; ++jl) {
                        #pragma unroll
                        for (int r = 0; r < RPB; ++r) {
                            accT[jl][r] = fmaf(scl[r][s], accS[jl][r], accT[jl][r]);
                            accS[jl][r] = 0.f;
                        }
                    }
                }
            }
        }

        // ---- prefetch next group's x into registers (hidden under the
        //      reduction + Sinkhorn + epilogue below) ----
        if (g + NBLK < ngroups) {
            const float4* xp = x4 + (g + NBLK) * RPB * 2048;
            #pragma unroll
            for (int r = 0; r < RPB; ++r)
                #pragma unroll
                for (int jj = 0; jj < 4; ++jj)
                    xr[r * 4 + jj] = xp[r * 2048 + t + 512 * jj];
        }

        // ---- reduce accT across lanes, fold bias, write H ----
        {
            #pragma unroll
            for (int m = 1; m < 64; m <<= 1) {
                #pragma unroll
                for (int jl = 0; jl < 3; ++jl)
                    #pragma unroll
                    for (int r = 0; r < RPB; ++r)
                        accT[jl][r] += __shfl_xor(accT[jl][r], m, 64);
            }
            if (lane == 0) {
                #pragma unroll
                for (int jl = 0; jl < 3; ++jl)
                    #pragma unroll
                    for (int r = 0; r < RPB; ++r)
                        H[r][3 * wave + jl] = accT[jl][r] + bias[jl];
            }
        }
        __syncthreads();

        // ---- Sinkhorn: every wave computes all 4 rows redundantly ----
        {
            const int r = lane >> 4;
            const int q = lane & 15;          // q = i*4 + jx
            float L = H[r][8 + q];
            float mx = L;
            mx = fmaxf(mx, __shfl_xor(mx, 1, 64));
            mx = fmaxf(mx, __shfl_xor(mx, 2, 64));
            mx = fmaxf(mx, __shfl_xor(mx, 4, 64));
            mx = fmaxf(mx, __shfl_xor(mx, 8, 64));
            float m = __expf(L - mx);
            #pragma unroll
            for (int it = 0; it < SINK_ITERS; ++it) {
                float rs = m + __shfl_xor(m, 1, 64);
                rs += __shfl_xor(rs, 2, 64);
                m = m * __builtin_amdgcn_rcpf(rs + EPS_F);   // row normalize
                float cs = m + __shfl_xor(m, 4, 64);
                cs += __shfl_xor(cs, 8, 64);
                m = m * __builtin_amdgcn_rcpf(cs + EPS_F);   // col normalize
            }
            MS[r][q] = m;                     // own-wave write / own-wave read
        }

        // ---- Phase D: mixing epilogue from LDS raw bf16 x ----
        #pragma unroll
        for (int r = 0; r < RPB; ++r) {
            const float4 hp = *reinterpret_cast<const float4*>(&H[r][0]);
            const float4 hq = *reinterpret_cast<const float4*>(&H[r][4]);
            float4 hrm[4];
            #pragma unroll
            for (int i = 0; i < 4; ++i)
                hrm[i] = *reinterpret_cast<const float4*>(&MS[r][4 * i]);
            float4 s[4];
            #pragma unroll
            for (int jj = 0; jj < 4; ++jj) {
                uint2 pk = *reinterpret_cast<const uint2*>(&xn[r][2 * t + 1024 * jj]);
                s[jj].x = __uint_as_float(pk.x << 16);
                s[jj].y = __uint_as_float(pk.x & 0xffff0000u);
                s[jj].z = __uint_as_float(pk.y << 16);
                s[jj].w = __uint_as_float(pk.y & 0xffff0000u);
            }
            float ax = hp.x*s[0].x + hp.y*s[1].x + hp.z*s[2].x + hp.w*s[3].x;
            float ay = hp.x*s[0].y + hp.y*s[1].y + hp.z*s[2].y + hp.w*s[3].y;
            float az = hp.x*s[0].z + hp.y*s[1].z + hp.z*s[2].z + hp.w*s[3].z;
            float aw = hp.x*s[0].w + hp.y*s[1].w + hp.z*s[2].w + hp.w*s[3].w;
            const float hqv[4] = {hq.x, hq.y, hq.z, hq.w};
            v4f* op = reinterpret_cast<v4f*>(out + (b0 + r) * NCF + 4 * t);
            #pragma unroll
            for (int i = 0; i < 4; ++i) {
                v4f o;
                o.x = hrm[i].x*s[0].x + hrm[i].y*s[1].x + hrm[i].z*s[2].x + hrm[i].w*s[3].x + hqv[i]*ax;
                o.y = hrm[i].x*s[0].y + hrm[i].y*s[1].y + hrm[i].z*s[2].y + hrm[i].w*s[3].y + hqv[i]*ay;
                o.z = hrm[i].x*s[0].z + hrm[i].y*s[1].z + hrm[i].z*s[2].z + hrm[i].w*s[3].z + hqv[i]*az;
                o.w = hrm[i].x*s[0].w + hrm[i].y*s[1].w + hrm[i].w*s[3].w + hrm[i].z*s[2].w + hqv[i]*aw;
                __builtin_nontemporal_store(o, op + i * 512);
            }
        }
        __syncthreads();   // protect xn/red before next iteration overwrites
    }
}

extern "C" void kernel_launch(void* const* d_in, const int* in_sizes, int n_in,
                              void* d_out, int out_size, void* d_ws, size_t ws_size,
                              hipStream_t stream)
{
    const float* x        = (const float*)d_in[0];
    const float* w        = (const float*)d_in[1];
    const float* phi_pre  = (const float*)d_in[2];
    const float* phi_post = (const float*)d_in[3];
    const float* phi_res  = (const float*)d_in[4];
    const float* b_pre    = (const float*)d_in[5];
    const float* b_post   = (const float*)d_in[6];
    const float* b_res    = (const float*)d_in[7];
    const float* a_pre    = (const float*)d_in[8];
    const float* a_post   = (const float*)d_in[9];
    const float* a_res    = (const float*)d_in[10];
    float* out = (float*)d_out;
    uint16_t* phiW = (uint16_t*)d_ws;   // NJ * NCF * 2 bytes = 384 KiB

    const int B = in_sizes[0] / NCF;    // 8192
    const int ngroups = B / RPB;        // 2048

    prep_phi_kernel<<<(NJ * NCF + 255) / 256, 256, 0, stream>>>(
        w, phi_pre, phi_post, phi_res, a_pre, a_post, a_res, phiW);

    mhc_main_kernel<<<NBLK, 512, 0, stream>>>(
        x, phiW, b_pre, b_post, b_res, out, ngroups);
}

// Round 15
// 166.500 us; speedup vs baseline: 1.4130x; 1.4130x over previous
//
#include <hip/hip_runtime.h>
#include <hip/hip_bf16.h>
#include <cstdint>

#define CH 2048
#define NCF 8192          // 4 * CH
#define NJ 24             // 4 pre + 4 post + 16 res
#define RPB 4             // batch rows per block
#define EPS_F 1e-5f
#define SINK_ITERS 20

typedef float v4f __attribute__((ext_vector_type(4)));

__device__ __forceinline__ uint32_t bf16rne(float f) {
    uint32_t u = __float_as_uint(f);
    return (u + 0x7fffu + ((u >> 16) & 1u)) >> 16;
}

// pack 2 f32 -> 2 bf16 in one instruction (lo -> [15:0], hi -> [31:16])
__device__ __forceinline__ uint32_t cvtpk(float lo, float hi) {
    uint32_t r;
    asm("v_cvt_pk_bf16_f32 %0, %1, %2" : "=v"(r) : "v"(lo), "v"(hi));
    return r;
}

// dot of 8 bf16 pairs (packed in uint4) via v_dot2_f32_bf16
__device__ __forceinline__ float dot8(const uint4& x, const uint4& p, float acc) {
    asm("v_dot2_f32_bf16 %0, %1, %2, %0" : "+v"(acc) : "v"(x.x), "v"(p.x));
    asm("v_dot2_f32_bf16 %0, %1, %2, %0" : "+v"(acc) : "v"(x.y), "v"(p.y));
    asm("v_dot2_f32_bf16 %0, %1, %2, %0" : "+v"(acc) : "v"(x.z), "v"(p.z));
    asm("v_dot2_f32_bf16 %0, %1, %2, %0" : "+v"(acc) : "v"(x.w), "v"(p.w));
    return acc;
}

// ---------------------------------------------------------------------------
// Prep: phiW[j][k] = bf16( alpha_j * w[k % CH] * phi_j[k] ),  j in [0,24)
// ---------------------------------------------------------------------------
__global__ void __launch_bounds__(256) prep_phi_kernel(
    const float* __restrict__ w,
    const float* __restrict__ phi_pre,
    const float* __restrict__ phi_post,
    const float* __restrict__ phi_res,
    const float* __restrict__ alpha_pre,
    const float* __restrict__ alpha_post,
    const float* __restrict__ alpha_res,
    uint16_t* __restrict__ phiW)
{
    int idx = blockIdx.x * 256 + threadIdx.x;
    if (idx >= NJ * NCF) return;
    int j = idx / NCF;
    int k = idx - j * NCF;
    int c = k & (CH - 1);
    float v, a;
    if (j < 4)      { v = phi_pre[j * NCF + k];        a = alpha_pre[0]; }
    else if (j < 8) { v = phi_post[(j - 4) * NCF + k]; a = alpha_post[0]; }
    else            { v = phi_res[(j - 8) * NCF + k];  a = alpha_res[0]; }
    phiW[idx] = (uint16_t)bf16rne(v * a * w[c]);
}

// ---------------------------------------------------------------------------
// Main fused kernel: 512 threads (8 waves), 4 rows/block, STREAM-PIPELINED.
// Per stream s: write rA (f32 regs) -> LDS bf16 + ss reduce -> barrier ->
// issue global loads for stream s+1 -> dot segment s (loads fly under dots).
// Only 4 float4 (16 VGPR) of x in flight at any time. Sinkhorn redundant on
// all waves; epilogue from LDS bf16 with nt stores. 5 barriers/block.
// ---------------------------------------------------------------------------
__global__ void __launch_bounds__(512, 2) mhc_main_kernel(
    const float* __restrict__ x,
    const uint16_t* __restrict__ phiW,
    const float* __restrict__ b_pre,
    const float* __restrict__ b_post,
    const float* __restrict__ b_res,
    float* __restrict__ out)
{
    const int t = threadIdx.x;
    const int lane = t & 63;
    const int wave = t >> 6;              // 0..7
    const long b0 = (long)blockIdx.x * RPB;

    __shared__ uint32_t xn[RPB][NCF / 2]; // raw bf16 x, 4 rows, 64 KiB
    __shared__ float redS[4][RPB][8];     // [stream][row][wave]
    __shared__ float H[RPB][24] __attribute__((aligned(16)));
    __shared__ float MS[RPB][16] __attribute__((aligned(16)));

    // per-wave projection-row biases (j = 3*wave + jl), hoisted
    float bias[3];
    #pragma unroll
    for (int jl = 0; jl < 3; ++jl) {
        int j = 3 * wave + jl;
        bias[jl] = (j < 4) ? b_pre[j] : (j < 8) ? b_post[j - 4] : b_res[j - 8];
    }

    const float4* xp = reinterpret_cast<const float4*>(x + b0 * NCF);
    const uint16_t* pw = phiW + (size_t)(wave * 3) * NCF;
    const int kl = 8 * lane;
    const uint4* xr0 = reinterpret_cast<const uint4*>(xn[0]);
    const uint4* xr1 = reinterpret_cast<const uint4*>(xn[1]);
    const uint4* xr2 = reinterpret_cast<const uint4*>(xn[2]);
    const uint4* xr3 = reinterpret_cast<const uint4*>(xn[3]);

    // prologue: load stream 0 (4 float4, one per row)
    float4 rA[RPB];
    #pragma unroll
    for (int r = 0; r < RPB; ++r) rA[r] = xp[r * 2048 + t];

    float accT[3][RPB] = {};

    #pragma unroll
    for (int s = 0; s < 4; ++s) {
        // ---- write stream s to LDS (bf16) + sum-of-squares reduce ----
        {
            float ssv[RPB];
            #pragma unroll
            for (int r = 0; r < RPB; ++r) {
                float4 v = rA[r];
                ssv[r] = v.x*v.x + v.y*v.y + v.z*v.z + v.w*v.w;
                *reinterpret_cast<uint2*>(&xn[r][2*t + 1024*s]) =
                    make_uint2(cvtpk(v.x, v.y), cvtpk(v.z, v.w));
            }
            #pragma unroll
            for (int m = 1; m < 64; m <<= 1)
                #pragma unroll
                for (int r = 0; r < RPB; ++r)
                    ssv[r] += __shfl_xor(ssv[r], m, 64);
            if (lane == 0) {
                #pragma unroll
                for (int r = 0; r < RPB; ++r) redS[s][r][wave] = ssv[r];
            }
        }
        __syncthreads();

        // ---- scl for stream s (redundant per thread) ----
        float sclS[RPB];
        #pragma unroll
        for (int r = 0; r < RPB; ++r) {
            float ss = 0.f;
            #pragma unroll
            for (int w8 = 0; w8 < 8; ++w8) ss += redS[s][r][w8];
            sclS[r] = rsqrtf(ss * (1.0f / CH) + EPS_F);
        }

        // ---- issue loads for stream s+1 (fly under the dots below) ----
        if (s < 3) {
            #pragma unroll
            for (int r = 0; r < RPB; ++r)
                rA[r] = xp[r * 2048 + 512 * (s + 1) + t];
        }

        // ---- dot segment s: u = 4s .. 4s+3, 2-step ping-pong ----
        float accS[3][RPB] = {};
        {
            const int u0 = 4 * s;
            int kA = 512 * u0 + kl;
            int iA = 64 * u0 + lane;
            uint4 pA0 = *reinterpret_cast<const uint4*>(pw + 0 * NCF + kA);
            uint4 pA1 = *reinterpret_cast<const uint4*>(pw + 1 * NCF + kA);
            uint4 pA2 = *reinterpret_cast<const uint4*>(pw + 2 * NCF + kA);
            uint4 xA0 = xr0[iA], xA1 = xr1[iA], xA2 = xr2[iA], xA3 = xr3[iA];

            #pragma unroll
            for (int du = 0; du < 4; du += 2) {
                const int u = u0 + du;
                const int iB = 64 * (u + 1) + lane;
                const int kB = 512 * (u + 1) + kl;
                uint4 pB0 = *reinterpret_cast<const uint4*>(pw + 0 * NCF + kB);
                uint4 pB1 = *reinterpret_cast<const uint4*>(pw + 1 * NCF + kB);
                uint4 pB2 = *reinterpret_cast<const uint4*>(pw + 2 * NCF + kB);
                uint4 xB0 = xr0[iB], xB1 = xr1[iB], xB2 = xr2[iB], xB3 = xr3[iB];

                accS[0][0] = dot8(xA0, pA0, accS[0][0]);
                accS[0][1] = dot8(xA1, pA0, accS[0][1]);
                accS[0][2] = dot8(xA2, pA0, accS[0][2]);
                accS[0][3] = dot8(xA3, pA0, accS[0][3]);
                accS[1][0] = dot8(xA0, pA1, accS[1][0]);
                accS[1][1] = dot8(xA1, pA1, accS[1][1]);
                accS[1][2] = dot8(xA2, pA1, accS[1][2]);
                accS[1][3] = dot8(xA3, pA1, accS[1][3]);
                accS[2][0] = dot8(xA0, pA2, accS[2][0]);
                accS[2][1] = dot8(xA1, pA2, accS[2][1]);
                accS[2][2] = dot8(xA2, pA2, accS[2][2]);
                accS[2][3] = dot8(xA3, pA2, accS[2][3]);

                if (du + 2 < 4) {
                    const int iA2 = 64 * (u + 2) + lane;
                    const int kA2 = 512 * (u + 2) + kl;
                    pA0 = *reinterpret_cast<const uint4*>(pw + 0 * NCF + kA2);
                    pA1 = *reinterpret_cast<const uint4*>(pw + 1 * NCF + kA2);
                    pA2 = *reinterpret_cast<const uint4*>(pw + 2 * NCF + kA2);
                    xA0 = xr0[iA2]; xA1 = xr1[iA2]; xA2 = xr2[iA2]; xA3 = xr3[iA2];
                }

                accS[0][0] = dot8(xB0, pB0, accS[0][0]);
                accS[0][1] = dot8(xB1, pB0, accS[0][1]);
                accS[0][2] = dot8(xB2, pB0, accS[0][2]);
                accS[0][3] = dot8(xB3, pB0, accS[0][3]);
                accS[1][0] = dot8(xB0, pB1, accS[1][0]);
                accS[1][1] = dot8(xB1, pB1, accS[1][1]);
                accS[1][2] = dot8(xB2, pB1, accS[1][2]);
                accS[1][3] = dot8(xB3, pB1, accS[1][3]);
                accS[2][0] = dot8(xB0, pB2, accS[2][0]);
                accS[2][1] = dot8(xB1, pB2, accS[2][1]);
                accS[2][2] = dot8(xB2, pB2, accS[2][2]);
                accS[2][3] = dot8(xB3, pB2, accS[2][3]);
            }
        }
        // fold RMS scale for this stream segment
        #pragma unroll
        for (int jl = 0; jl < 3; ++jl)
            #pragma unroll
            for (int r = 0; r < RPB; ++r)
                accT[jl][r] = fmaf(sclS[r], accS[jl][r], accT[jl][r]);
    }

    // ---- reduce accT across lanes, fold bias, write H ----
    {
        #pragma unroll
        for (int m = 1; m < 64; m <<= 1) {
            #pragma unroll
            for (int jl = 0; jl < 3; ++jl)
                #pragma unroll
                for (int r = 0; r < RPB; ++r)
                    accT[jl][r] += __shfl_xor(accT[jl][r], m, 64);
        }
        if (lane == 0) {
            #pragma unroll
            for (int jl = 0; jl < 3; ++jl)
                #pragma unroll
                for (int r = 0; r < RPB; ++r)
                    H[r][3 * wave + jl] = accT[jl][r] + bias[jl];
        }
    }
    __syncthreads();

    // ---- Sinkhorn: every wave computes all 4 rows redundantly ----
    {
        const int r = lane >> 4;
        const int q = lane & 15;          // q = i*4 + jx
        float L = H[r][8 + q];
        float mx = L;
        mx = fmaxf(mx, __shfl_xor(mx, 1, 64));
        mx = fmaxf(mx, __shfl_xor(mx, 2, 64));
        mx = fmaxf(mx, __shfl_xor(mx, 4, 64));
        mx = fmaxf(mx, __shfl_xor(mx, 8, 64));
        float m = __expf(L - mx);
        #pragma unroll
        for (int it = 0; it < SINK_ITERS; ++it) {
            float rs = m + __shfl_xor(m, 1, 64);
            rs += __shfl_xor(rs, 2, 64);
            m = m * __builtin_amdgcn_rcpf(rs + EPS_F);   // row normalize
            float cs = m + __shfl_xor(m, 4, 64);
            cs += __shfl_xor(cs, 8, 64);
            m = m * __builtin_amdgcn_rcpf(cs + EPS_F);   // col normalize
        }
        MS[r][q] = m;                     // own-wave write / own-wave read
    }

    // ---- Phase D: mixing epilogue from LDS raw bf16 x ----
    #pragma unroll
    for (int r = 0; r < RPB; ++r) {
        const float4 hp = *reinterpret_cast<const float4*>(&H[r][0]);
        const float4 hq = *reinterpret_cast<const float4*>(&H[r][4]);
        float4 hrm[4];
        #pragma unroll
        for (int i = 0; i < 4; ++i)
            hrm[i] = *reinterpret_cast<const float4*>(&MS[r][4 * i]);
        float4 sv[4];
        #pragma unroll
        for (int jj = 0; jj < 4; ++jj) {
            uint2 pk = *reinterpret_cast<const uint2*>(&xn[r][2 * t + 1024 * jj]);
            sv[jj].x = __uint_as_float(pk.x << 16);
            sv[jj].y = __uint_as_float(pk.x & 0xffff0000u);
            sv[jj].z = __uint_as_float(pk.y << 16);
            sv[jj].w = __uint_as_float(pk.y & 0xffff0000u);
        }
        float ax = hp.x*sv[0].x + hp.y*sv[1].x + hp.z*sv[2].x + hp.w*sv[3].x;
        float ay = hp.x*sv[0].y + hp.y*sv[1].y + hp.z*sv[2].y + hp.w*sv[3].y;
        float az = hp.x*sv[0].z + hp.y*sv[1].z + hp.z*sv[2].z + hp.w*sv[3].z;
        float aw = hp.x*sv[0].w + hp.y*sv[1].w + hp.z*sv[2].w + hp.w*sv[3].w;
        const float hqv[4] = {hq.x, hq.y, hq.z, hq.w};
        v4f* op = reinterpret_cast<v4f*>(out + (b0 + r) * NCF + 4 * t);
        #pragma unroll
        for (int i = 0; i < 4; ++i) {
            v4f o;
            o.x = hrm[i].x*sv[0].x + hrm[i].y*sv[1].x + hrm[i].z*sv[2].x + hrm[i].w*sv[3].x + hqv[i]*ax;
            o.y = hrm[i].x*sv[0].y + hrm[i].y*sv[1].y + hrm[i].z*sv[2].y + hrm[i].w*sv[3].y + hqv[i]*ay;
            o.z = hrm[i].x*sv[0].z + hrm[i].y*sv[1].z + hrm[i].z*sv[2].z + hrm[i].w*sv[3].z + hqv[i]*az;
            o.w = hrm[i].x*sv[0].w + hrm[i].y*sv[1].w + hrm[i].z*sv[2].w + hrm[i].w*sv[3].w + hqv[i]*aw;
            __builtin_nontemporal_store(o, op + i * 512);
        }
    }
}

extern "C" void kernel_launch(void* const* d_in, const int* in_sizes, int n_in,
                              void* d_out, int out_size, void* d_ws, size_t ws_size,
                              hipStream_t stream)
{
    const float* x        = (const float*)d_in[0];
    const float* w        = (const float*)d_in[1];
    const float* phi_pre  = (const float*)d_in[2];
    const float* phi_post = (const float*)d_in[3];
    const float* phi_res  = (const float*)d_in[4];
    const float* b_pre    = (const float*)d_in[5];
    const float* b_post   = (const float*)d_in[6];
    const float* b_res    = (const float*)d_in[7];
    const float* a_pre    = (const float*)d_in[8];
    const float* a_post   = (const float*)d_in[9];
    const float* a_res    = (const float*)d_in[10];
    float* out = (float*)d_out;
    uint16_t* phiW = (uint16_t*)d_ws;   // NJ * NCF * 2 bytes = 384 KiB

    const int B = in_sizes[0] / NCF;    // 8192

    prep_phi_kernel<<<(NJ * NCF + 255) / 256, 256, 0, stream>>>(
        w, phi_pre, phi_post, phi_res, a_pre, a_post, a_res, phiW);

    mhc_main_kernel<<<B / RPB, 512, 0, stream>>>(
        x, phiW, b_pre, b_post, b_res, out);
}

// Round 16
// 135.025 us; speedup vs baseline: 1.7424x; 1.2331x over previous
//
#include <hip/hip_runtime.h>
#include <hip/hip_bf16.h>
#include <cstdint>

#define CH 2048
#define NCF 8192          // 4 * CH
#define NJ 24             // 4 pre + 4 post + 16 res
#define RPB 4             // batch rows per block
#define EPS_F 1e-5f
#define SINK_ITERS 20

typedef float v4f __attribute__((ext_vector_type(4)));

__device__ __forceinline__ uint32_t bf16rne(float f) {
    uint32_t u = __float_as_uint(f);
    return (u + 0x7fffu + ((u >> 16) & 1u)) >> 16;
}

// pack 2 f32 -> 2 bf16 in one instruction (lo -> [15:0], hi -> [31:16])
__device__ __forceinline__ uint32_t cvtpk(float lo, float hi) {
    uint32_t r;
    asm("v_cvt_pk_bf16_f32 %0, %1, %2" : "=v"(r) : "v"(lo), "v"(hi));
    return r;
}

// dot of 8 bf16 pairs (packed in uint4) via v_dot2_f32_bf16
__device__ __forceinline__ float dot8(const uint4& x, const uint4& p, float acc) {
    asm("v_dot2_f32_bf16 %0, %1, %2, %0" : "+v"(acc) : "v"(x.x), "v"(p.x));
    asm("v_dot2_f32_bf16 %0, %1, %2, %0" : "+v"(acc) : "v"(x.y), "v"(p.y));
    asm("v_dot2_f32_bf16 %0, %1, %2, %0" : "+v"(acc) : "v"(x.z), "v"(p.z));
    asm("v_dot2_f32_bf16 %0, %1, %2, %0" : "+v"(acc) : "v"(x.w), "v"(p.w));
    return acc;
}

// ---------------------------------------------------------------------------
// Prep: phiW[j][k] = bf16( alpha_j * w[k % CH] * phi_j[k] ),  j in [0,24)
// ---------------------------------------------------------------------------
__global__ void __launch_bounds__(256) prep_phi_kernel(
    const float* __restrict__ w,
    const float* __restrict__ phi_pre,
    const float* __restrict__ phi_post,
    const float* __restrict__ phi_res,
    const float* __restrict__ alpha_pre,
    const float* __restrict__ alpha_post,
    const float* __restrict__ alpha_res,
    uint16_t* __restrict__ phiW)
{
    int idx = blockIdx.x * 256 + threadIdx.x;
    if (idx >= NJ * NCF) return;
    int j = idx / NCF;
    int k = idx - j * NCF;
    int c = k & (CH - 1);
    float v, a;
    if (j < 4)      { v = phi_pre[j * NCF + k];        a = alpha_pre[0]; }
    else if (j < 8) { v = phi_post[(j - 4) * NCF + k]; a = alpha_post[0]; }
    else            { v = phi_res[(j - 8) * NCF + k];  a = alpha_res[0]; }
    phiW[idx] = (uint16_t)bf16rne(v * a * w[c]);
}

// ---------------------------------------------------------------------------
// Main fused kernel: 512 threads (8 waves), FOUR batch rows per block.
// LDS holds raw bf16 x for 4 rows (64 KiB). RMS scale folded into the dot
// accumulation at stream-segment boundaries. Phase B: 2-step ping-pong phi
// prefetch with v_dot2_f32_bf16. Sinkhorn: all waves redundant, broadcast
// via MS LDS. Epilogue: per-row 4x4 M = hrm + hq (x) hp applied to x.
// 2 barriers total.
// ---------------------------------------------------------------------------
__global__ void __launch_bounds__(512) mhc_main_kernel(
    const float* __restrict__ x,
    const uint16_t* __restrict__ phiW,
    const float* __restrict__ b_pre,
    const float* __restrict__ b_post,
    const float* __restrict__ b_res,
    float* __restrict__ out)
{
    const int t = threadIdx.x;
    const int lane = t & 63;
    const int wave = t >> 6;              // 0..7
    const long b0 = (long)blockIdx.x * RPB;

    __shared__ uint32_t xn[RPB][NCF / 2]; // raw bf16 x, 4 rows, 64 KiB
    __shared__ float4 red[RPB][8];
    __shared__ float H[RPB][24] __attribute__((aligned(16)));
    __shared__ float MS[RPB][16] __attribute__((aligned(16)));

    // ---- Phase A: global -> LDS (raw bf16), sum-of-squares per stream ----
    // All 16 loads issued before any processing (max read-burst MLP).
    {
        const float4* xp = reinterpret_cast<const float4*>(x + b0 * NCF);
        float4 a[RPB][4];
        #pragma unroll
        for (int r = 0; r < RPB; ++r)
            #pragma unroll
            for (int jj = 0; jj < 4; ++jj)
                a[r][jj] = xp[r * 2048 + t + 512 * jj];

        float ss[RPB][4];
        #pragma unroll
        for (int r = 0; r < RPB; ++r) {
            #pragma unroll
            for (int jj = 0; jj < 4; ++jj) {
                float4 v = a[r][jj];
                ss[r][jj] = v.x*v.x + v.y*v.y + v.z*v.z + v.w*v.w;
                *reinterpret_cast<uint2*>(&xn[r][2*t + 1024*jj]) =
                    make_uint2(cvtpk(v.x, v.y), cvtpk(v.z, v.w));
            }
        }
        #pragma unroll
        for (int m = 1; m < 64; m <<= 1) {
            #pragma unroll
            for (int r = 0; r < RPB; ++r)
                #pragma unroll
                for (int jj = 0; jj < 4; ++jj)
                    ss[r][jj] += __shfl_xor(ss[r][jj], m, 64);
        }
        if (lane == 0) {
            #pragma unroll
            for (int r = 0; r < RPB; ++r)
                red[r][wave] = make_float4(ss[r][0], ss[r][1], ss[r][2], ss[r][3]);
        }
    }
    __syncthreads();

    // ---- SCL computed redundantly per thread (broadcast LDS reads) ----
    float scl[RPB][4];
    #pragma unroll
    for (int r = 0; r < RPB; ++r) {
        float sx = 0.f, sy = 0.f, sz = 0.f, sw = 0.f;
        #pragma unroll
        for (int w8 = 0; w8 < 8; ++w8) {
            float4 v = red[r][w8];
            sx += v.x; sy += v.y; sz += v.z; sw += v.w;
        }
        scl[r][0] = rsqrtf(sx * (1.0f / CH) + EPS_F);
        scl[r][1] = rsqrtf(sy * (1.0f / CH) + EPS_F);
        scl[r][2] = rsqrtf(sz * (1.0f / CH) + EPS_F);
        scl[r][3] = rsqrtf(sw * (1.0f / CH) + EPS_F);
    }

    // ---- Phase B: wave w dots 4 raw rows against phi rows 3w..3w+2 ----
    // 16 steps of 512 elems; 2-step ping-pong; scl folded per stream segment.
    float accT[3][RPB] = {};
    float accS[3][RPB] = {};
    {
        const uint16_t* pw = phiW + (size_t)(wave * 3) * NCF;
        const int kl = 8 * lane;
        const uint4* xr0 = reinterpret_cast<const uint4*>(xn[0]);
        const uint4* xr1 = reinterpret_cast<const uint4*>(xn[1]);
        const uint4* xr2 = reinterpret_cast<const uint4*>(xn[2]);
        const uint4* xr3 = reinterpret_cast<const uint4*>(xn[3]);

        uint4 pA0 = *reinterpret_cast<const uint4*>(pw + 0 * NCF + kl);
        uint4 pA1 = *reinterpret_cast<const uint4*>(pw + 1 * NCF + kl);
        uint4 pA2 = *reinterpret_cast<const uint4*>(pw + 2 * NCF + kl);
        uint4 xA0 = xr0[lane], xA1 = xr1[lane], xA2 = xr2[lane], xA3 = xr3[lane];

        #pragma unroll
        for (int u = 0; u < 16; u += 2) {
            const int iB = 64 * (u + 1) + lane;
            const int kB = 512 * (u + 1) + kl;
            uint4 pB0 = *reinterpret_cast<const uint4*>(pw + 0 * NCF + kB);
            uint4 pB1 = *reinterpret_cast<const uint4*>(pw + 1 * NCF + kB);
            uint4 pB2 = *reinterpret_cast<const uint4*>(pw + 2 * NCF + kB);
            uint4 xB0 = xr0[iB], xB1 = xr1[iB], xB2 = xr2[iB], xB3 = xr3[iB];

            accS[0][0] = dot8(xA0, pA0, accS[0][0]);
            accS[0][1] = dot8(xA1, pA0, accS[0][1]);
            accS[0][2] = dot8(xA2, pA0, accS[0][2]);
            accS[0][3] = dot8(xA3, pA0, accS[0][3]);
            accS[1][0] = dot8(xA0, pA1, accS[1][0]);
            accS[1][1] = dot8(xA1, pA1, accS[1][1]);
            accS[1][2] = dot8(xA2, pA1, accS[1][2]);
            accS[1][3] = dot8(xA3, pA1, accS[1][3]);
            accS[2][0] = dot8(xA0, pA2, accS[2][0]);
            accS[2][1] = dot8(xA1, pA2, accS[2][1]);
            accS[2][2] = dot8(xA2, pA2, accS[2][2]);
            accS[2][3] = dot8(xA3, pA2, accS[2][3]);

            if (u + 2 < 16) {
                const int iA = 64 * (u + 2) + lane;
                const int kA = 512 * (u + 2) + kl;
                pA0 = *reinterpret_cast<const uint4*>(pw + 0 * NCF + kA);
                pA1 = *reinterpret_cast<const uint4*>(pw + 1 * NCF + kA);
                pA2 = *reinterpret_cast<const uint4*>(pw + 2 * NCF + kA);
                xA0 = xr0[iA]; xA1 = xr1[iA]; xA2 = xr2[iA]; xA3 = xr3[iA];
            }

            accS[0][0] = dot8(xB0, pB0, accS[0][0]);
            accS[0][1] = dot8(xB1, pB0, accS[0][1]);
            accS[0][2] = dot8(xB2, pB0, accS[0][2]);
            accS[0][3] = dot8(xB3, pB0, accS[0][3]);
            accS[1][0] = dot8(xB0, pB1, accS[1][0]);
            accS[1][1] = dot8(xB1, pB1, accS[1][1]);
            accS[1][2] = dot8(xB2, pB1, accS[1][2]);
            accS[1][3] = dot8(xB3, pB1, accS[1][3]);
            accS[2][0] = dot8(xB0, pB2, accS[2][0]);
            accS[2][1] = dot8(xB1, pB2, accS[2][1]);
            accS[2][2] = dot8(xB2, pB2, accS[2][2]);
            accS[2][3] = dot8(xB3, pB2, accS[2][3]);

            if (((u + 1) & 3) == 3) {               // end of stream segment
                const int s = (u + 1) >> 2;
                #pragma unroll
                for (int jl = 0; jl < 3; ++jl) {
                    #pragma unroll
                    for (int r = 0; r < RPB; ++r) {
                        accT[jl][r] = fmaf(scl[r][s], accS[jl][r], accT[jl][r]);
                        accS[jl][r] = 0.f;
                    }
                }
            }
        }
    }
    {
        #pragma unroll
        for (int m = 1; m < 64; m <<= 1) {
            #pragma unroll
            for (int jl = 0; jl < 3; ++jl) {
                #pragma unroll
                for (int r = 0; r < RPB; ++r)
                    accT[jl][r] += __shfl_xor(accT[jl][r], m, 64);
            }
        }
        if (lane == 0) {                 // fold bias, write H directly
            #pragma unroll
            for (int jl = 0; jl < 3; ++jl) {
                int j = 3 * wave + jl;
                float bias;
                if (j < 4)      bias = b_pre[j];
                else if (j < 8) bias = b_post[j - 4];
                else            bias = b_res[j - 8];
                #pragma unroll
                for (int r = 0; r < RPB; ++r) H[r][j] = accT[jl][r] + bias;
            }
        }
    }
    __syncthreads();

    // ---- Sinkhorn: every wave computes all 4 rows redundantly (16-lane
    // groups); identical-value writes to MS (benign race, own-wave read).
    {
        const int r = lane >> 4;
        const int q = lane & 15;          // q = i*4 + jx
        float L = H[r][8 + q];
        float mx = L;
        mx = fmaxf(mx, __shfl_xor(mx, 1, 64));
        mx = fmaxf(mx, __shfl_xor(mx, 2, 64));
        mx = fmaxf(mx, __shfl_xor(mx, 4, 64));
        mx = fmaxf(mx, __shfl_xor(mx, 8, 64));
        float m = __expf(L - mx);
        #pragma unroll
        for (int it = 0; it < SINK_ITERS; ++it) {
            float rs = m + __shfl_xor(m, 1, 64);
            rs += __shfl_xor(rs, 2, 64);
            m = m * __builtin_amdgcn_rcpf(rs + EPS_F);   // row normalize
            float cs = m + __shfl_xor(m, 4, 64);
            cs += __shfl_xor(cs, 8, 64);
            m = m * __builtin_amdgcn_rcpf(cs + EPS_F);   // col normalize
        }
        MS[r][q] = m;
    }

    // ---- Phase D: out[i,c] = sum_j M[i,j]*x[j,c], M = hrm + hq (x) hp ----
    #pragma unroll
    for (int r = 0; r < RPB; ++r) {
        const float4 hp = *reinterpret_cast<const float4*>(&H[r][0]);
        const float4 hq = *reinterpret_cast<const float4*>(&H[r][4]);
        float4 M[4];
        #pragma unroll
        for (int i = 0; i < 4; ++i) {
            float4 hrm = *reinterpret_cast<const float4*>(&MS[r][4 * i]);
            const float q = (i == 0) ? hq.x : (i == 1) ? hq.y : (i == 2) ? hq.z : hq.w;
            M[i].x = fmaf(q, hp.x, hrm.x);
            M[i].y = fmaf(q, hp.y, hrm.y);
            M[i].z = fmaf(q, hp.z, hrm.z);
            M[i].w = fmaf(q, hp.w, hrm.w);
        }
        float4 s[4];
        #pragma unroll
        for (int jj = 0; jj < 4; ++jj) {
            uint2 pk = *reinterpret_cast<const uint2*>(&xn[r][2 * t + 1024 * jj]);
            s[jj].x = __uint_as_float(pk.x << 16);
            s[jj].y = __uint_as_float(pk.x & 0xffff0000u);
            s[jj].z = __uint_as_float(pk.y << 16);
            s[jj].w = __uint_as_float(pk.y & 0xffff0000u);
        }
        v4f* op = reinterpret_cast<v4f*>(out + (b0 + r) * NCF + 4 * t);
        #pragma unroll
        for (int i = 0; i < 4; ++i) {
            v4f o;
            o.x = M[i].x*s[0].x + M[i].y*s[1].x + M[i].z*s[2].x + M[i].w*s[3].x;
            o.y = M[i].x*s[0].y + M[i].y*s[1].y + M[i].z*s[2].y + M[i].w*s[3].y;
            o.z = M[i].x*s[0].z + M[i].y*s[1].z + M[i].z*s[2].z + M[i].w*s[3].z;
            o.w = M[i].x*s[0].w + M[i].y*s[1].w + M[i].z*s[2].w + M[i].w*s[3].w;
            __builtin_nontemporal_store(o, op + i * 512);
        }
    }
}

extern "C" void kernel_launch(void* const* d_in, const int* in_sizes, int n_in,
                              void* d_out, int out_size, void* d_ws, size_t ws_size,
                              hipStream_t stream)
{
    const float* x        = (const float*)d_in[0];
    const float* w        = (const float*)d_in[1];
    const float* phi_pre  = (const float*)d_in[2];
    const float* phi_post = (const float*)d_in[3];
    const float* phi_res  = (const float*)d_in[4];
    const float* b_pre    = (const float*)d_in[5];
    const float* b_post   = (const float*)d_in[6];
    const float* b_res    = (const float*)d_in[7];
    const float* a_pre    = (const float*)d_in[8];
    const float* a_post   = (const float*)d_in[9];
    const float* a_res    = (const float*)d_in[10];
    float* out = (float*)d_out;
    uint16_t* phiW = (uint16_t*)d_ws;   // NJ * NCF * 2 bytes = 384 KiB

    const int B = in_sizes[0] / NCF;    // 8192

    prep_phi_kernel<<<(NJ * NCF + 255) / 256, 256, 0, stream>>>(
        w, phi_pre, phi_post, phi_res, a_pre, a_post, a_res, phiW);

    mhc_main_kernel<<<B / RPB, 512, 0, stream>>>(
        x, phiW, b_pre, b_post, b_res, out);
}